// Round 1
// 179.571 us; speedup vs baseline: 1.0235x; 1.0235x over previous
//
#include <hip/hip_runtime.h>

// GridSample1d, align_corners=True, border padding.
// inp [64,64,4096] f32, grid [64,8192] f32, out [64,64,8192] f32.
//
// R5: fold CPB=2 channels per block. The grid row + index math (li/w1) are
// identical for every channel of the same n, so computing them per-(n,c)
// block was 64x redundant. One block now stages TWO input rows (32 KB LDS,
// still 4 blocks/CU = 128 KB <= 160 KB, occupancy unchanged at 16 waves/CU),
// computes indices once, and gathers+lerps both rows. Halves index VALU per
// output, halves grid L2 reads, halves barrier count. Staging (16B
// global_load_lds, linear dest) and NT float4 stores unchanged from R4.
//
// dur_us accounting (R4 rocprof): top dispatches are 2x ~78us 512MiB poison
// fills; kernel itself ~27.5us vs ~19.5-21us NT-write floor. This round
// attacks the ~6-8us of non-write overhead.

constexpr int N_    = 64;
constexpr int C_    = 64;
constexpr int L_IN  = 4096;
constexpr int L_OUT = 8192;

constexpr int BLOCK = 256;
constexpr int CPB   = 2;                  // channels per block
constexpr int EPT   = L_OUT / BLOCK;      // 32 grid points per thread
constexpr int NCH   = EPT / 4;            // 8 float4 chunks
constexpr int NBLOCKS = N_ * C_ / CPB;    // 2048

typedef float f32x4 __attribute__((ext_vector_type(4)));

__global__ __launch_bounds__(BLOCK, 4) void gs1d_kernel(
    const float* __restrict__ inp, const float* __restrict__ grid,
    float* __restrict__ out)
{
    __shared__ float row[CPB][L_IN];  // 32 KB

    const int tid = threadIdx.x;
    const int bid = blockIdx.x;           // n*32 + c/2
    const int n   = bid >> 5;
    const int c0  = (bid & 31) * CPB;

    // Stage CPB input rows -> LDS: 8 x (256 lanes x 16 B) async DMA.
    // LDS dest semantics: wave-uniform base + lane*16 (m97/m104) -> linear.
    const float* src = inp + (size_t)(n * C_ + c0) * L_IN;
#pragma unroll
    for (int r = 0; r < CPB; ++r) {
#pragma unroll
        for (int k = 0; k < 4; ++k) {
            int e     = (k * BLOCK + tid) * 4;          // per-lane float index
            int lbase = (k * BLOCK + (tid & ~63)) * 4;  // wave-uniform float index
            __builtin_amdgcn_global_load_lds(
                (const __attribute__((address_space(1))) void*)(src + r * L_IN + e),
                (__attribute__((address_space(3))) void*)(&row[r][lbase]),
                16, 0, 0);
        }
    }

    const float* grow = grid + (size_t)n * L_OUT;

    // Pre-barrier: all grid loads + index math in registers; this VALU phase
    // (plus the grid-load latency) covers the 32 KB DMA's in-flight time.
    int   li[EPT];
    float w1[EPT];
#pragma unroll
    for (int h = 0; h < NCH; ++h) {
        float4 g = *reinterpret_cast<const float4*>(grow + h * (BLOCK * 4) + 4 * tid);
        const float* gp = &g.x;
#pragma unroll
        for (int j = 0; j < 4; ++j) {
            // exact reference op order: ((g+1)*0.5)*(L-1), clip, floor
            float x = (gp[j] + 1.0f) * 0.5f * (float)(L_IN - 1);
            x = fminf(fmaxf(x, 0.0f), (float)(L_IN - 1));
            float xf = floorf(x);
            int   i0 = (int)xf;
            float w  = x - xf;
            // boundary: at i0==L-1 shift to (li=L-2, w1=1) so the
            // unconditional lerp a + w1*(b-a) stays exact.
            li[h * 4 + j] = min(i0, L_IN - 2);
            w1[h * 4 + j] = (i0 >= L_IN - 1) ? 1.0f : w;
        }
    }

    __syncthreads();  // DMA latency already covered by the index phase

    float* orow = out + (size_t)(n * C_ + c0) * L_OUT;

    // Post-barrier: LDS gather + lerp for BOTH rows off the shared indices,
    // nontemporal coalesced float4 stores (output is never re-read).
#pragma unroll
    for (int h = 0; h < NCH; ++h) {
        f32x4 o0, o1;
#pragma unroll
        for (int j = 0; j < 4; ++j) {
            int   p  = h * 4 + j;
            float a0 = row[0][li[p]];       // ds_read2_b32 pair
            float b0 = row[0][li[p] + 1];
            float a1 = row[1][li[p]];       // same vaddr, offset:16384
            float b1 = row[1][li[p] + 1];
            o0[j] = fmaf(w1[p], b0 - a0, a0);
            o1[j] = fmaf(w1[p], b1 - a1, a1);
        }
        __builtin_nontemporal_store(o0,
            reinterpret_cast<f32x4*>(orow + h * (BLOCK * 4) + 4 * tid));
        __builtin_nontemporal_store(o1,
            reinterpret_cast<f32x4*>(orow + L_OUT + h * (BLOCK * 4) + 4 * tid));
    }
}

extern "C" void kernel_launch(void* const* d_in, const int* in_sizes, int n_in,
                              void* d_out, int out_size, void* d_ws, size_t ws_size,
                              hipStream_t stream) {
    const float* inp  = (const float*)d_in[0];
    const float* grid = (const float*)d_in[1];
    float* out = (float*)d_out;
    gs1d_kernel<<<NBLOCKS, BLOCK, 0, stream>>>(inp, grid, out);
}